// Round 1
// baseline (123.465 us; speedup 1.0000x reference)
//
#include <hip/hip_runtime.h>

// Tensor-train per-token contraction:
//   y[t, p,q,o] = relu( bias[p,q,o] + sum_{i,j,k,r,s} a[p,i,r] b[q,j,r,s] c[o,k,s] x[t, i,j,k] )
// x: [65536, 512] (i*64+j*8+k), out: [65536, 1024] (p*128+q*16+o), all fp32.
//
// One wave per token. Lane roles per stage:
//   Stage A: lane=(j,k)  computes t1[p,r]  (128 FMA)
//   Stage B: lane=(p,k)  computes t2[q,s]  (256 FMA)
//   Stage C: lane=(q,p)  computes y[o=0..15] (256 FMA) + bias + relu + store
// Transposes between stages go through a per-wave 1024-float LDS buffer with a
// bit-packed/XOR address so write and read sides are both <=2-way bank aliased:
//   T1 element (p,r,j,k): addr = r*512 + (j>>2)*256 + p*32 + k*4 + ((j^p)&3)
//   T2 element (q,s,p,k): addr = s*512 + (k>>2)*256 + q*32 + p*4 + ((k^q)&3)

#define NTOK (16 * 4096)

__global__ __launch_bounds__(256) void tt_contract_kernel(
    const float* __restrict__ x,
    const float* __restrict__ a,    // [8][8][2]  p,i,r
    const float* __restrict__ b,    // [8][8][2][2] q,j,r,s
    const float* __restrict__ c,    // [16][8][2] o,k,s
    const float* __restrict__ bias, // [8][8][16] p,q,o
    float* __restrict__ out)
{
    __shared__ float lds[4][1024];
    const int l = threadIdx.x & 63;
    const int w = threadIdx.x >> 6;
    const int token = blockIdx.x * 4 + w;
    float* buf = lds[w];

    // ---------------- Stage A: lane = (j,k) ----------------
    {
        const int j = l >> 3, k = l & 7;
        const float* xp = x + (size_t)token * 512 + j * 8 + k;
        float xi[8];
#pragma unroll
        for (int i = 0; i < 8; ++i) xi[i] = xp[i * 64];   // coalesced dword loads

        float t1[16]; // [p][r]
#pragma unroll
        for (int p = 0; p < 8; ++p)
#pragma unroll
            for (int r = 0; r < 2; ++r) {
                float acc = 0.f;
#pragma unroll
                for (int i = 0; i < 8; ++i)
                    acc = fmaf(a[p * 16 + i * 2 + r], xi[i], acc);
                t1[p * 2 + r] = acc;
            }

#pragma unroll
        for (int p = 0; p < 8; ++p)
#pragma unroll
            for (int r = 0; r < 2; ++r)
                buf[r * 512 + (j >> 2) * 256 + p * 32 + k * 4 + ((j ^ p) & 3)] =
                    t1[p * 2 + r];
    }
    __syncthreads();

    // ---------------- Stage B: lane = (p,k) ----------------
    float t2[16]; // [q][s]
    {
        const int p = l >> 3, k = l & 7;
        float u[16]; // [r][j]
#pragma unroll
        for (int r = 0; r < 2; ++r)
#pragma unroll
            for (int j = 0; j < 8; ++j)
                u[r * 8 + j] =
                    buf[r * 512 + (j >> 2) * 256 + p * 32 + k * 4 + ((j ^ p) & 3)];

        __syncthreads(); // all reads of t1 done before overwriting buf

#pragma unroll
        for (int q = 0; q < 8; ++q)
#pragma unroll
            for (int s = 0; s < 2; ++s) {
                float acc = 0.f;
#pragma unroll
                for (int j = 0; j < 8; ++j)
#pragma unroll
                    for (int r = 0; r < 2; ++r)
                        acc = fmaf(b[q * 32 + j * 4 + r * 2 + s], u[r * 8 + j], acc);
                t2[q * 2 + s] = acc;
            }

#pragma unroll
        for (int q = 0; q < 8; ++q)
#pragma unroll
            for (int s = 0; s < 2; ++s)
                buf[s * 512 + (k >> 2) * 256 + q * 32 + p * 4 + ((k ^ q) & 3)] =
                    t2[q * 2 + s];
    }
    __syncthreads();

    // ---------------- Stage C: lane = (q,p) ----------------
    {
        const int q = l >> 3, p = l & 7;
        float v[16]; // [s][k]
#pragma unroll
        for (int s = 0; s < 2; ++s)
#pragma unroll
            for (int k = 0; k < 8; ++k)
                v[s * 8 + k] =
                    buf[s * 512 + (k >> 2) * 256 + q * 32 + p * 4 + ((k ^ q) & 3)];

        // bias init (vectorized, L1-hot)
        const float4* bp4 = (const float4*)(bias + (p * 8 + q) * 16);
        float y[16];
#pragma unroll
        for (int m = 0; m < 4; ++m) {
            float4 bv = bp4[m];
            y[m * 4 + 0] = bv.x; y[m * 4 + 1] = bv.y;
            y[m * 4 + 2] = bv.z; y[m * 4 + 3] = bv.w;
        }

#pragma unroll
        for (int o = 0; o < 16; ++o) {
            float acc = y[o];
#pragma unroll
            for (int k = 0; k < 8; ++k)
#pragma unroll
                for (int s = 0; s < 2; ++s)
                    acc = fmaf(c[o * 16 + k * 2 + s], v[s * 8 + k], acc);
            y[o] = acc > 0.f ? acc : 0.f;
        }

        float* op = out + (size_t)token * 1024 + p * 128 + q * 16;
#pragma unroll
        for (int m = 0; m < 4; ++m) {
            float4 sv = make_float4(y[m * 4 + 0], y[m * 4 + 1],
                                    y[m * 4 + 2], y[m * 4 + 3]);
            *(float4*)(op + m * 4) = sv;
        }
    }
}

extern "C" void kernel_launch(void* const* d_in, const int* in_sizes, int n_in,
                              void* d_out, int out_size, void* d_ws, size_t ws_size,
                              hipStream_t stream) {
    const float* x    = (const float*)d_in[0];
    const float* a    = (const float*)d_in[1];
    const float* b    = (const float*)d_in[2];
    const float* c    = (const float*)d_in[3];
    const float* bias = (const float*)d_in[4];
    float* out = (float*)d_out;

    // 65536 tokens, 1 wave/token, 4 waves/block -> 16384 blocks
    tt_contract_kernel<<<NTOK / 4, 256, 0, stream>>>(x, a, b, c, bias, out);
}